// Round 1
// 224.790 us; speedup vs baseline: 1.0526x; 1.0526x over previous
//
#include <hip/hip_runtime.h>
#include <stdint.h>

// UKF (affine motion => exact Kalman filter). Inputs fp32, outputs fp32.
//
// R5 lesson: only wave-instruction-level contiguity is 1x write amp =>
// OCTET REDUNDANCY: 8 lanes per batch element compute the same recursion,
// lane j stages a 4-step window; a flush writes 128B contiguous per b per
// row (8 lanes x 16B in ONE instruction).
//
// R6 (this round):
//  - PHASE-STAGGERED flushes: group b flushes when ((sub + (b&7)) & 7)==7.
//    Previously all waves flushed at the same sub -> instantaneous write
//    demand ~8x the 1.5 TB/s average > 6.3 TB/s achievable -> store-queue
//    backpressure surfaced as vmcnt waits before re-staging the same regs.
//    Staggering smooths writes to ~1.6 TB/s steady and shrinks each
//    wait-before-redefine to 1/8 of the data, issued a full sub earlier.
//  - M = K*S = Pxz*S^-1*S = Pxz = a[:,0:2] exactly: the M block (16
//    FLOP/step) deleted; P-update uses a directly.
//  - 1/det via v_rcp_f32 (1 ulp, tolerance is 1.5e-2) instead of the
//    full-precision divide sequence on the critical path.
//  - P-update as fma chains; folded 0.5*DT^2.

static constexpr float DTc = 0.1f;
static constexpr float HDT2 = 0.5f * DTc * DTc;

__global__ __launch_bounds__(256, 2) void ukf_oct(
    const float* __restrict__ meas,   // (B, 2, S)
    const float* __restrict__ stin,   // (B, 4)
    const float* __restrict__ covin,  // (B, 4, 4)
    const float* __restrict__ ctrl,   // (B, S, 2)
    const float* __restrict__ Qp,     // (4,4)
    const float* __restrict__ Rp,     // (2,2)
    float* __restrict__ out,          // preds (B,2,S) | states (B,4,S) | covs (B,4,4,S)
    int B, int S)
{
    const int tid = blockIdx.x * 256 + threadIdx.x;
    const int b   = tid >> 3;          // 8 lanes per batch element
    const int myj = tid & 7;           // my 4-step window within a 32-step tile
    if (b >= B) return;
    const int phase = b & 7;           // flush-phase stagger across b-groups

    float4 s4 = *reinterpret_cast<const float4*>(stin + (size_t)b * 4);
    float x0 = s4.x, x1 = s4.y, x2 = s4.z, x3 = s4.w;

    float p00, p01, p02, p03, p11, p12, p13, p22, p23, p33;
    {
        const float4* pc = reinterpret_cast<const float4*>(covin + (size_t)b * 16);
        float4 r0 = pc[0], r1 = pc[1], r2 = pc[2], r3 = pc[3];
        p00 = r0.x; p01 = r0.y; p02 = r0.z; p03 = r0.w;
        p11 = r1.y; p12 = r1.z; p13 = r1.w; p22 = r2.z; p23 = r2.w; p33 = r3.w;
    }
    float q00, q01, q02, q03, q11, q12, q13, q22, q23, q33;
    {
        const float4* pq = reinterpret_cast<const float4*>(Qp);
        float4 r0 = pq[0], r1 = pq[1], r2 = pq[2], r3 = pq[3];
        q00 = r0.x; q01 = r0.y; q02 = r0.z; q03 = r0.w;
        q11 = r1.y; q12 = r1.z; q13 = r1.w; q22 = r2.z; q23 = r2.w; q33 = r3.w;
    }
    float R00, R01, R10, R11;
    {
        float4 r = *reinterpret_cast<const float4*>(Rp);
        R00 = r.x; R01 = r.y; R10 = r.z; R11 = r.w;
    }

    const float4* pm0 = reinterpret_cast<const float4*>(meas + (size_t)b * 2 * S);
    const float4* pm1 = reinterpret_cast<const float4*>(meas + (size_t)b * 2 * S + S);
    const float4* pu  = reinterpret_cast<const float4*>(ctrl + (size_t)b * S * 2);

    float* bp = out + (size_t)b * 2 * S;                       // preds rows
    float* bs = out + (size_t)B * 2 * S + (size_t)b * 4 * S;   // states rows
    float* bc = out + (size_t)B * 6 * S + (size_t)b * 16 * S;  // covs rows

    const int NT = S / 4;              // 4-step sub-tiles (25 for S=100)

    // staging: lane's 4-step window of {preds0,1, states0..3, P-triangle 0..9}
    float4 sgp0, sgp1, sgs0, sgs1, sgs2, sgs3;
    float4 sgt[10];

    float4 m0 = pm0[0], m1 = pm1[0], u0 = pu[0], u1 = pu[1];

    for (int sub = 0; sub < NT; ++sub) {
        float4 nm0 = make_float4(0, 0, 0, 0), nm1 = nm0, nu0 = nm0, nu1 = nm0;
        if (sub + 1 < NT) {
            nm0 = pm0[sub + 1];
            nm1 = pm1[sub + 1];
            nu0 = pu[2 * sub + 2];
            nu1 = pu[2 * sub + 3];
        }

        const float zb0[4] = { m0.x, m0.y, m0.z, m0.w };
        const float zb1[4] = { m1.x, m1.y, m1.z, m1.w };
        const float uxb[4] = { u0.x, u0.z, u1.x, u1.z };
        const float uyb[4] = { u0.y, u0.w, u1.y, u1.w };

        const bool take = (((sub + phase) & 7) == myj);

#pragma unroll
        for (int k = 0; k < 4; ++k) {
            const float ux = uxb[k], uy = uyb[k];

            const float xp0 = x0 + DTc * x2 + HDT2 * ux;
            const float xp1 = x1 + DTc * x3 + HDT2 * uy;
            const float xp2 = x2 + DTc * ux;
            const float xp3 = x3 + DTc * uy;

            const float FP00 = p00 + DTc * p02, FP01 = p01 + DTc * p12;
            const float FP02 = p02 + DTc * p22, FP03 = p03 + DTc * p23;
            const float FP11 = p11 + DTc * p13, FP12 = p12 + DTc * p23;
            const float FP13 = p13 + DTc * p33;

            const float a00 = FP00 + DTc * FP02, a01 = FP01 + DTc * FP03;
            const float a02 = FP02, a03 = FP03;
            const float a11 = FP11 + DTc * FP13, a12 = FP12, a13 = FP13;
            const float a22 = p22, a23 = p23, a33 = p33;

            const float s00 = a00 + R00, s01 = a01 + R01;
            const float s10 = a01 + R10, s11 = a11 + R11;
            const float rdet = __builtin_amdgcn_rcpf(s00 * s11 - s01 * s10);
            const float i00 =  s11 * rdet, i01 = -s01 * rdet;
            const float i10 = -s10 * rdet, i11 =  s00 * rdet;

            const float K00 = a00*i00 + a01*i10, K01 = a00*i01 + a01*i11;
            const float K10 = a01*i00 + a11*i10, K11 = a01*i01 + a11*i11;
            const float K20 = a02*i00 + a12*i10, K21 = a02*i01 + a12*i11;
            const float K30 = a03*i00 + a13*i10, K31 = a03*i01 + a13*i11;

            const float in0 = zb0[k] - xp0, in1 = zb1[k] - xp1;
            const float xn0 = xp0 + K00*in0 + K01*in1;
            const float xn1 = xp1 + K10*in0 + K11*in1;
            const float xn2 = xp2 + K20*in0 + K21*in1;
            const float xn3 = xp3 + K30*in0 + K31*in1;

            // M = K*S = Pxz*S^-1*S = Pxz = a[:,0:2] exactly -> P = a + Q - Pxz*K^T
            p00 = (a00 + q00) - a00*K00 - a01*K01;
            p01 = (a01 + q01) - a00*K10 - a01*K11;
            p02 = (a02 + q02) - a00*K20 - a01*K21;
            p03 = (a03 + q03) - a00*K30 - a01*K31;
            p11 = (a11 + q11) - a01*K10 - a11*K11;
            p12 = (a12 + q12) - a01*K20 - a11*K21;
            p13 = (a13 + q13) - a01*K30 - a11*K31;
            p22 = (a22 + q22) - a02*K20 - a12*K21;
            p23 = (a23 + q23) - a02*K30 - a12*K31;
            p33 = (a33 + q33) - a03*K30 - a13*K31;

            x0 = xn0; x1 = xn1; x2 = xn2; x3 = xn3;

            if (take) {  // exec-masked register captures of this lane's window
                if (k == 0) {
                    sgp0.x=xp0; sgp1.x=xp1; sgs0.x=xn0; sgs1.x=xn1; sgs2.x=xn2; sgs3.x=xn3;
                    sgt[0].x=p00; sgt[1].x=p01; sgt[2].x=p02; sgt[3].x=p03; sgt[4].x=p11;
                    sgt[5].x=p12; sgt[6].x=p13; sgt[7].x=p22; sgt[8].x=p23; sgt[9].x=p33;
                } else if (k == 1) {
                    sgp0.y=xp0; sgp1.y=xp1; sgs0.y=xn0; sgs1.y=xn1; sgs2.y=xn2; sgs3.y=xn3;
                    sgt[0].y=p00; sgt[1].y=p01; sgt[2].y=p02; sgt[3].y=p03; sgt[4].y=p11;
                    sgt[5].y=p12; sgt[6].y=p13; sgt[7].y=p22; sgt[8].y=p23; sgt[9].y=p33;
                } else if (k == 2) {
                    sgp0.z=xp0; sgp1.z=xp1; sgs0.z=xn0; sgs1.z=xn1; sgs2.z=xn2; sgs3.z=xn3;
                    sgt[0].z=p00; sgt[1].z=p01; sgt[2].z=p02; sgt[3].z=p03; sgt[4].z=p11;
                    sgt[5].z=p12; sgt[6].z=p13; sgt[7].z=p22; sgt[8].z=p23; sgt[9].z=p33;
                } else {
                    sgp0.w=xp0; sgp1.w=xp1; sgs0.w=xn0; sgs1.w=xn1; sgs2.w=xn2; sgs3.w=xn3;
                    sgt[0].w=p00; sgt[1].w=p01; sgt[2].w=p02; sgt[3].w=p03; sgt[4].w=p11;
                    sgt[5].w=p12; sgt[6].w=p13; sgt[7].w=p22; sgt[8].w=p23; sgt[9].w=p33;
                }
            }
        }

        // Staggered flush: exactly one b-group per wave flushes each sub.
        // 8 contiguous active lanes x 16B = 128B contiguous per row per b
        // in ONE instruction — same contiguity as before, smooth traffic.
        if (((sub + phase) & 7) == 7) {
            const int w = sub - 7 + myj;   // this lane's window (sub index)
            if (w >= 0) {                  // first flush of a group is partial
                const int off = w * 4;     // float offset in row
                *reinterpret_cast<float4*>(bp + 0 * S + off) = sgp0;
                *reinterpret_cast<float4*>(bp + 1 * S + off) = sgp1;
                *reinterpret_cast<float4*>(bs + 0 * S + off) = sgs0;
                *reinterpret_cast<float4*>(bs + 1 * S + off) = sgs1;
                *reinterpret_cast<float4*>(bs + 2 * S + off) = sgs2;
                *reinterpret_cast<float4*>(bs + 3 * S + off) = sgs3;
                const int map[16] = {0,1,2,3, 1,4,5,6, 2,5,7,8, 3,6,8,9};
#pragma unroll
                for (int r = 0; r < 16; r++)
                    *reinterpret_cast<float4*>(bc + r * S + off) = sgt[map[r]];
            }
        }

        m0 = nm0; m1 = nm1; u0 = nu0; u1 = nu1;
    }

    // tail: windows captured after this group's last in-loop flush.
    // lane's windows are subs == r (mod 8); last one is wl. It was flushed
    // in-loop iff the covering flush sub (wl + 7 - myj) fit inside [0,NT).
    {
        const int r = (myj - phase) & 7;
        if (r < NT) {
            const int wl = r + (((NT - 1 - r) >> 3) << 3);
            if (wl + 7 - myj > NT - 1) {
                const int off = wl * 4;
                *reinterpret_cast<float4*>(bp + 0 * S + off) = sgp0;
                *reinterpret_cast<float4*>(bp + 1 * S + off) = sgp1;
                *reinterpret_cast<float4*>(bs + 0 * S + off) = sgs0;
                *reinterpret_cast<float4*>(bs + 1 * S + off) = sgs1;
                *reinterpret_cast<float4*>(bs + 2 * S + off) = sgs2;
                *reinterpret_cast<float4*>(bs + 3 * S + off) = sgs3;
                const int map[16] = {0,1,2,3, 1,4,5,6, 2,5,7,8, 3,6,8,9};
#pragma unroll
                for (int rr = 0; rr < 16; rr++)
                    *reinterpret_cast<float4*>(bc + rr * S + off) = sgt[map[rr]];
            }
        }
    }
}

extern "C" void kernel_launch(void* const* d_in, const int* in_sizes, int n_in,
                              void* d_out, int out_size, void* d_ws, size_t ws_size,
                              hipStream_t stream) {
    // Identify inputs by element count (order-robust):
    int iR = -1, iQ = -1, iMeas = -1, iCtrl = -1, iState = -1, iCov = -1;
    for (int i = 0; i < n_in; i++) {
        if (in_sizes[i] == 4 && iR < 0) iR = i;
        else if (in_sizes[i] == 16 && iQ < 0) iQ = i;
    }
    for (int i = 0; i < n_in && iMeas < 0; i++) {
        if (i == iR || i == iQ) continue;
        for (int j = i + 1; j < n_in; j++) {
            if (j == iR || j == iQ) continue;
            if (in_sizes[i] == in_sizes[j]) { iMeas = i; iCtrl = j; break; }
        }
    }
    int rem[2], nrem = 0;
    for (int i = 0; i < n_in && nrem < 2; i++) {
        if (i == iR || i == iQ || i == iMeas || i == iCtrl) continue;
        rem[nrem++] = i;
    }
    if (in_sizes[rem[0]] > in_sizes[rem[1]]) { iCov = rem[0]; iState = rem[1]; }
    else                                     { iCov = rem[1]; iState = rem[0]; }

    const float* meas  = (const float*)d_in[iMeas];
    const float* stin  = (const float*)d_in[iState];
    const float* covin = (const float*)d_in[iCov];
    const float* ctrl  = (const float*)d_in[iCtrl];
    const float* Qp    = (const float*)d_in[iQ];
    const float* Rp    = (const float*)d_in[iR];
    float* out = (float*)d_out;

    const int B = in_sizes[iState] / 4;
    const int S = in_sizes[iMeas] / (2 * B);

    // 8 threads per batch element, 256-thread blocks
    const int total = B * 8;
    ukf_oct<<<dim3((total + 255) / 256), dim3(256), 0, stream>>>(
        meas, stin, covin, ctrl, Qp, Rp, out, B, S);
}

// Round 2
// 220.398 us; speedup vs baseline: 1.0736x; 1.0199x over previous
//
#include <hip/hip_runtime.h>
#include <stdint.h>

// UKF (affine motion => exact Kalman filter). Inputs fp32, outputs fp32.
//
// R5: only wave-instruction-level contiguity is 1x write amp => OCTET
// groups: 8 lanes per batch element run the same recursion; a flush writes
// 128B contiguous per b per output row (8 lanes x 16B in ONE instruction).
// R6: phase-staggered flushes (+10us), M=K*S=Pxz identity, v_rcp.
// R7 (this round): LDS temporal staging replaces register staging.
//   - Register staging forced a store->redefine s_waitcnt EVERY sub (the
//     22 flush stores read the same VGPRs the next sub's capture rewrites
//     ~60 instr later) and 64 masked selects/sub at the end of the P-chain.
//   - Now lane 0 of each group ds_writes the current step's 16 outputs to
//     lds[group][slot][row][k] (slot = capturing lane, (sub+phase)&7).
//     Flush: lane j ds_read_b128 x16 from slot j -> 22 global stores from
//     FRESH regs (no hazard: regs not redefined until next flush, 8 subs
//     later). No barriers needed: each group's LDS region is touched only
//     by its own wave (same-wave lgkmcnt ordering).
//   - Bank padding: slot stride 68 dwords (flush lanes hit distinct bank
//     quads: 68*j%32=4j), group stride 548 dwords (capture lanes worst
//     case 2-way = free per m136). 16B alignment for b128 preserved.
//   - LDS 32 groups * 548 dw * 4B = 70144 B/block -> 2 blocks/CU (137KB
//     of 160KB), occupancy unchanged at 2 waves/SIMD (grid-capped).

static constexpr float DTc  = 0.1f;
static constexpr float HDT2 = 0.5f * DTc * DTc;
static constexpr int SSTRIDE = 68;                 // dwords per window slot
static constexpr int GSTRIDE = 8 * SSTRIDE + 4;    // 548 dwords per group
static constexpr int LDS_BYTES = 32 * GSTRIDE * 4; // 70144 B per block

__global__ __launch_bounds__(256, 2) void ukf_lds(
    const float* __restrict__ meas,   // (B, 2, S)
    const float* __restrict__ stin,   // (B, 4)
    const float* __restrict__ covin,  // (B, 4, 4)
    const float* __restrict__ ctrl,   // (B, S, 2)
    const float* __restrict__ Qp,     // (4,4)
    const float* __restrict__ Rp,     // (2,2)
    float* __restrict__ out,          // preds (B,2,S) | states (B,4,S) | covs (B,4,4,S)
    int B, int S)
{
    extern __shared__ float lds[];

    const int tid = blockIdx.x * 256 + threadIdx.x;
    const int b   = tid >> 3;              // 8 lanes per batch element
    const int myj = threadIdx.x & 7;       // lane role within group
    if (b >= B) return;
    const int phase = b & 7;               // flush-phase stagger across groups
    const int g = threadIdx.x >> 3;        // group index within block (0..31)

    float* ldsg = lds + g * GSTRIDE;       // this group's LDS region
    float* fl   = ldsg + myj * SSTRIDE;    // my flush-read slot (sub-invariant)

    float4 s4 = *reinterpret_cast<const float4*>(stin + (size_t)b * 4);
    float x0 = s4.x, x1 = s4.y, x2 = s4.z, x3 = s4.w;

    float p00, p01, p02, p03, p11, p12, p13, p22, p23, p33;
    {
        const float4* pc = reinterpret_cast<const float4*>(covin + (size_t)b * 16);
        float4 r0 = pc[0], r1 = pc[1], r2 = pc[2], r3 = pc[3];
        p00 = r0.x; p01 = r0.y; p02 = r0.z; p03 = r0.w;
        p11 = r1.y; p12 = r1.z; p13 = r1.w; p22 = r2.z; p23 = r2.w; p33 = r3.w;
    }
    float q00, q01, q02, q03, q11, q12, q13, q22, q23, q33;
    {
        const float4* pq = reinterpret_cast<const float4*>(Qp);
        float4 r0 = pq[0], r1 = pq[1], r2 = pq[2], r3 = pq[3];
        q00 = r0.x; q01 = r0.y; q02 = r0.z; q03 = r0.w;
        q11 = r1.y; q12 = r1.z; q13 = r1.w; q22 = r2.z; q23 = r2.w; q33 = r3.w;
    }
    float R00, R01, R10, R11;
    {
        float4 r = *reinterpret_cast<const float4*>(Rp);
        R00 = r.x; R01 = r.y; R10 = r.z; R11 = r.w;
    }

    const float4* pm0 = reinterpret_cast<const float4*>(meas + (size_t)b * 2 * S);
    const float4* pm1 = reinterpret_cast<const float4*>(meas + (size_t)b * 2 * S + S);
    const float4* pu  = reinterpret_cast<const float4*>(ctrl + (size_t)b * S * 2);

    float* bp = out + (size_t)b * 2 * S;                       // preds rows
    float* bs = out + (size_t)B * 2 * S + (size_t)b * 4 * S;   // states rows
    float* bc = out + (size_t)B * 6 * S + (size_t)b * 16 * S;  // covs rows

    const int NT = S / 4;              // 4-step sub-tiles (25 for S=100)

    float4 m0 = pm0[0], m1 = pm1[0], u0 = pu[0], u1 = pu[1];

    for (int sub = 0; sub < NT; ++sub) {
        float4 nm0 = make_float4(0, 0, 0, 0), nm1 = nm0, nu0 = nm0, nu1 = nm0;
        if (sub + 1 < NT) {
            nm0 = pm0[sub + 1];
            nm1 = pm1[sub + 1];
            nu0 = pu[2 * sub + 2];
            nu1 = pu[2 * sub + 3];
        }

        const float zb0[4] = { m0.x, m0.y, m0.z, m0.w };
        const float zb1[4] = { m1.x, m1.y, m1.z, m1.w };
        const float uxb[4] = { u0.x, u0.z, u1.x, u1.z };
        const float uyb[4] = { u0.y, u0.w, u1.y, u1.w };

        // Capture slot for this sub (group-uniform; lane 0 writes for the group)
        float* cap = ldsg + ((sub + phase) & 7) * SSTRIDE;

#pragma unroll
        for (int k = 0; k < 4; ++k) {
            const float ux = uxb[k], uy = uyb[k];

            const float xp0 = x0 + DTc * x2 + HDT2 * ux;
            const float xp1 = x1 + DTc * x3 + HDT2 * uy;
            const float xp2 = x2 + DTc * ux;
            const float xp3 = x3 + DTc * uy;

            const float FP00 = p00 + DTc * p02, FP01 = p01 + DTc * p12;
            const float FP02 = p02 + DTc * p22, FP03 = p03 + DTc * p23;
            const float FP11 = p11 + DTc * p13, FP12 = p12 + DTc * p23;
            const float FP13 = p13 + DTc * p33;

            const float a00 = FP00 + DTc * FP02, a01 = FP01 + DTc * FP03;
            const float a02 = FP02, a03 = FP03;
            const float a11 = FP11 + DTc * FP13, a12 = FP12, a13 = FP13;
            const float a22 = p22, a23 = p23, a33 = p33;

            const float s00 = a00 + R00, s01 = a01 + R01;
            const float s10 = a01 + R10, s11 = a11 + R11;
            const float rdet = __builtin_amdgcn_rcpf(s00 * s11 - s01 * s10);
            const float i00 =  s11 * rdet, i01 = -s01 * rdet;
            const float i10 = -s10 * rdet, i11 =  s00 * rdet;

            const float K00 = a00*i00 + a01*i10, K01 = a00*i01 + a01*i11;
            const float K10 = a01*i00 + a11*i10, K11 = a01*i01 + a11*i11;
            const float K20 = a02*i00 + a12*i10, K21 = a02*i01 + a12*i11;
            const float K30 = a03*i00 + a13*i10, K31 = a03*i01 + a13*i11;

            const float in0 = zb0[k] - xp0, in1 = zb1[k] - xp1;
            const float xn0 = xp0 + K00*in0 + K01*in1;
            const float xn1 = xp1 + K10*in0 + K11*in1;
            const float xn2 = xp2 + K20*in0 + K21*in1;
            const float xn3 = xp3 + K30*in0 + K31*in1;

            // M = K*S = Pxz*S^-1*S = Pxz = a[:,0:2] -> P = a + Q - Pxz*K^T
            p00 = (a00 + q00) - a00*K00 - a01*K01;
            p01 = (a01 + q01) - a00*K10 - a01*K11;
            p02 = (a02 + q02) - a00*K20 - a01*K21;
            p03 = (a03 + q03) - a00*K30 - a01*K31;
            p11 = (a11 + q11) - a01*K10 - a11*K11;
            p12 = (a12 + q12) - a01*K20 - a11*K21;
            p13 = (a13 + q13) - a01*K30 - a11*K31;
            p22 = (a22 + q22) - a02*K20 - a12*K21;
            p23 = (a23 + q23) - a02*K30 - a12*K31;
            p33 = (a33 + q33) - a03*K30 - a13*K31;

            x0 = xn0; x1 = xn1; x2 = xn2; x3 = xn3;

            // Capture: one lane per group writes current step into the slot.
            // Layout [row][k] so flush reads ds_read_b128 per row. Pairs of
            // consecutive rows fuse into ds_write2_b32 (same base, imm offs).
            if (myj == 0) {
                cap[ 0*4 + k] = xp0;  cap[ 1*4 + k] = xp1;
                cap[ 2*4 + k] = xn0;  cap[ 3*4 + k] = xn1;
                cap[ 4*4 + k] = xn2;  cap[ 5*4 + k] = xn3;
                cap[ 6*4 + k] = p00;  cap[ 7*4 + k] = p01;
                cap[ 8*4 + k] = p02;  cap[ 9*4 + k] = p03;
                cap[10*4 + k] = p11;  cap[11*4 + k] = p12;
                cap[12*4 + k] = p13;  cap[13*4 + k] = p22;
                cap[14*4 + k] = p23;  cap[15*4 + k] = p33;
            }
        }

        // Staggered flush: one group per wave per sub; lane j reads slot j
        // (window w = sub-7+j), stores 8 lanes x 16B = 128B contiguous/row.
        {
            const int w = sub - 7 + myj;
            if ((((sub + phase) & 7) == 7) && (w >= 0)) {
                float4 rw[16];
#pragma unroll
                for (int r = 0; r < 16; r++)
                    rw[r] = *reinterpret_cast<const float4*>(fl + r * 4);
                const int off = w * 4;
                *reinterpret_cast<float4*>(bp + 0 * S + off) = rw[0];
                *reinterpret_cast<float4*>(bp + 1 * S + off) = rw[1];
                *reinterpret_cast<float4*>(bs + 0 * S + off) = rw[2];
                *reinterpret_cast<float4*>(bs + 1 * S + off) = rw[3];
                *reinterpret_cast<float4*>(bs + 2 * S + off) = rw[4];
                *reinterpret_cast<float4*>(bs + 3 * S + off) = rw[5];
                const int map[16] = {0,1,2,3, 1,4,5,6, 2,5,7,8, 3,6,8,9};
#pragma unroll
                for (int r = 0; r < 16; r++)
                    *reinterpret_cast<float4*>(bc + r * S + off) = rw[6 + map[r]];
            }
        }

        m0 = nm0; m1 = nm1; u0 = nu0; u1 = nu1;
    }

    // Tail: lane's windows are subs == r (mod 8); last one wl was flushed
    // in-loop iff its covering flush sub (wl + 7 - myj) fit inside [0,NT).
    {
        const int r = (myj - phase) & 7;
        if (r < NT) {
            const int wl = r + (((NT - 1 - r) >> 3) << 3);
            if (wl + 7 - myj > NT - 1) {
                float4 rw[16];
#pragma unroll
                for (int rr = 0; rr < 16; rr++)
                    rw[rr] = *reinterpret_cast<const float4*>(fl + rr * 4);
                const int off = wl * 4;
                *reinterpret_cast<float4*>(bp + 0 * S + off) = rw[0];
                *reinterpret_cast<float4*>(bp + 1 * S + off) = rw[1];
                *reinterpret_cast<float4*>(bs + 0 * S + off) = rw[2];
                *reinterpret_cast<float4*>(bs + 1 * S + off) = rw[3];
                *reinterpret_cast<float4*>(bs + 2 * S + off) = rw[4];
                *reinterpret_cast<float4*>(bs + 3 * S + off) = rw[5];
                const int map[16] = {0,1,2,3, 1,4,5,6, 2,5,7,8, 3,6,8,9};
#pragma unroll
                for (int rr = 0; rr < 16; rr++)
                    *reinterpret_cast<float4*>(bc + rr * S + off) = rw[6 + map[rr]];
            }
        }
    }
}

extern "C" void kernel_launch(void* const* d_in, const int* in_sizes, int n_in,
                              void* d_out, int out_size, void* d_ws, size_t ws_size,
                              hipStream_t stream) {
    // Identify inputs by element count (order-robust):
    int iR = -1, iQ = -1, iMeas = -1, iCtrl = -1, iState = -1, iCov = -1;
    for (int i = 0; i < n_in; i++) {
        if (in_sizes[i] == 4 && iR < 0) iR = i;
        else if (in_sizes[i] == 16 && iQ < 0) iQ = i;
    }
    for (int i = 0; i < n_in && iMeas < 0; i++) {
        if (i == iR || i == iQ) continue;
        for (int j = i + 1; j < n_in; j++) {
            if (j == iR || j == iQ) continue;
            if (in_sizes[i] == in_sizes[j]) { iMeas = i; iCtrl = j; break; }
        }
    }
    int rem[2], nrem = 0;
    for (int i = 0; i < n_in && nrem < 2; i++) {
        if (i == iR || i == iQ || i == iMeas || i == iCtrl) continue;
        rem[nrem++] = i;
    }
    if (in_sizes[rem[0]] > in_sizes[rem[1]]) { iCov = rem[0]; iState = rem[1]; }
    else                                     { iCov = rem[1]; iState = rem[0]; }

    const float* meas  = (const float*)d_in[iMeas];
    const float* stin  = (const float*)d_in[iState];
    const float* covin = (const float*)d_in[iCov];
    const float* ctrl  = (const float*)d_in[iCtrl];
    const float* Qp    = (const float*)d_in[iQ];
    const float* Rp    = (const float*)d_in[iR];
    float* out = (float*)d_out;

    const int B = in_sizes[iState] / 4;
    const int S = in_sizes[iMeas] / (2 * B);

    // 8 threads per batch element, 256-thread blocks, 70144 B dynamic LDS
    const int total = B * 8;
    ukf_lds<<<dim3((total + 255) / 256), dim3(256), LDS_BYTES, stream>>>(
        meas, stin, covin, ctrl, Qp, Rp, out, B, S);
}